// Round 5
// baseline (137.605 us; speedup 1.0000x reference)
//
#include <hip/hip_runtime.h>
#include <hip/hip_bf16.h>

#define BT      8192
#define DIN     2048
#define DOUT    2048
#define NEXP    8
#define RANK    8
#define KX      2112         /* DIN + NEXP*RANK */
#define NSUB    66           /* KX / 32 K-subtiles */
#define NSPLIT  4            /* K-split for the h-GEMM */
#define HLD     72           /* HP leading dim (8 router rows unused + 64 rank) */
#define SCALING 1.0f         /* ALPHA / RANK = 8/8 */

typedef __bf16 bf16x8 __attribute__((ext_vector_type(8)));
typedef __bf16 bf16x4 __attribute__((ext_vector_type(4)));
typedef float  f32x4  __attribute__((ext_vector_type(4)));

/* ---- ws layout (bytes) ---- */
#define XB_OFF     0
#define XB_BYTES   (BT * KX * 2)
#define WB_OFF     (XB_OFF + XB_BYTES)
#define WB_BYTES   (DOUT * KX * 2)
#define ACAT_OFF   (WB_OFF + WB_BYTES)
#define ACAT_BYTES (128 * DIN * 2)
#define HP_OFF     (ACAT_OFF + ACAT_BYTES)
#define HP_BYTES   (NSPLIT * BT * HLD * 4)
#define LOG_OFF    (HP_OFF + HP_BYTES)

__device__ __forceinline__ void gload_lds16(const void* g, void* l) {
    __builtin_amdgcn_global_load_lds(
        (__attribute__((address_space(1))) void*)(g),
        (__attribute__((address_space(3))) void*)(l),
        16, 0, 0);
}

#define MFMA16(a, b, c) __builtin_amdgcn_mfma_f32_16x16x32_bf16((a), (b), (c), 0, 0, 0)

/* ---------------- prep: weights -> bf16 staged layouts ---------------- */
__global__ __launch_bounds__(256) void mole_prep(
    const float* __restrict__ Wf, const float* __restrict__ Bm,
    const float* __restrict__ Wr, const float* __restrict__ A,
    __bf16* __restrict__ WB, __bf16* __restrict__ ACAT)
{
    const int i = blockIdx.x * 256 + threadIdx.x;
    const int R1 = DOUT * (DIN / 4);
    const int R2 = DOUT * 64;
    if (i < R1) {
        const int o = i >> 9, c4 = i & 511;
        float4 v = ((const float4*)Wf)[(size_t)o * 512 + c4];
        bf16x4 b; b[0] = (__bf16)v.x; b[1] = (__bf16)v.y; b[2] = (__bf16)v.z; b[3] = (__bf16)v.w;
        *(bf16x4*)&WB[(size_t)o * KX + (c4 << 2)] = b;
    } else if (i < R1 + R2) {
        const int j = i - R1;
        const int o = j >> 6, c = j & 63;
        const int e = c >> 3, r = c & 7;
        WB[(size_t)o * KX + DIN + c] = (__bf16)Bm[((size_t)e * DOUT + o) * RANK + r];
    } else {
        const int j = i - (R1 + R2);
        const int r = j >> 9, c4 = j & 511;
        float4 v;
        if (r < 8)        v = ((const float4*)Wr)[(size_t)r * 512 + c4];
        else if (r < 72)  v = ((const float4*)A)[(size_t)(r - 8) * 512 + c4];
        else              v = make_float4(0.f, 0.f, 0.f, 0.f);
        bf16x4 b; b[0] = (__bf16)v.x; b[1] = (__bf16)v.y; b[2] = (__bf16)v.z; b[3] = (__bf16)v.w;
        *(bf16x4*)&ACAT[(size_t)r * DIN + (c4 << 2)] = b;
    }
}

/* ------- convert x -> bf16 (stride KX) + exact fp32 router logits ------- */
__global__ __launch_bounds__(512) void mole_convert_x_logits(
    const float* __restrict__ x, const float* __restrict__ Wr,
    const float* __restrict__ br,
    __bf16* __restrict__ XB, float* __restrict__ LOG)
{
    const int t   = blockIdx.x;
    const int tid = threadIdx.x;
    float4 v = ((const float4*)x)[(size_t)t * 512 + tid];
    bf16x4 b; b[0] = (__bf16)v.x; b[1] = (__bf16)v.y; b[2] = (__bf16)v.z; b[3] = (__bf16)v.w;
    *(bf16x4*)&XB[(size_t)t * KX + (tid << 2)] = b;

    float p[NEXP];
    #pragma unroll
    for (int e = 0; e < NEXP; ++e) {
        float4 w4 = ((const float4*)Wr)[e * 512 + tid];
        p[e] = v.x * w4.x + v.y * w4.y + v.z * w4.z + v.w * w4.w;
    }
    #pragma unroll
    for (int e = 0; e < NEXP; ++e)
        #pragma unroll
        for (int off = 32; off > 0; off >>= 1)
            p[e] += __shfl_down(p[e], off);

    __shared__ float red[8][NEXP];
    const int wv = tid >> 6, ln = tid & 63;
    if (ln == 0) {
        #pragma unroll
        for (int e = 0; e < NEXP; ++e) red[wv][e] = p[e];
    }
    __syncthreads();
    if (tid < NEXP) {
        float s = br[tid];
        #pragma unroll
        for (int w = 0; w < 8; ++w) s += red[w][tid];
        LOG[(size_t)t * NEXP + tid] = s;
    }
}

/* ------- 128x128 MFMA GEMM (m97 structure), used for the h-GEMM ------- */
__global__ __launch_bounds__(256) void mole_gemm_bt(
    const __bf16* __restrict__ A, int lda,
    const __bf16* __restrict__ B, int ldb,
    float* __restrict__ C, int ldc, int colMax,
    int kChunk, long long cZStride)
{
    __shared__ __align__(16) __bf16 As[128][32];
    __shared__ __align__(16) __bf16 Bs[128][32];

    const int tid = threadIdx.x;
    const int wv  = tid >> 6;
    const int ln  = tid & 63;
    const int wr  = wv >> 1, wc = wv & 1;

    const size_t m0 = (size_t)blockIdx.x * 128;
    const size_t n0 = (size_t)blockIdx.y * 128;
    const int kStart = blockIdx.z * kChunk;
    C += (long long)blockIdx.z * cZStride;

    const int srow = (wv << 4) + (ln >> 2);
    const int scol = (ln & 3) << 3;
    const __bf16* gA0 = A + (m0 + srow) * (size_t)lda + kStart + scol;
    const __bf16* gA1 = gA0 + (size_t)64 * lda;
    const __bf16* gB0 = B + (n0 + srow) * (size_t)ldb + kStart + scol;
    const __bf16* gB1 = gB0 + (size_t)64 * ldb;
    __bf16* lA0 = &As[(wv << 4)][0];
    __bf16* lA1 = &As[64 + (wv << 4)][0];
    __bf16* lB0 = &Bs[(wv << 4)][0];
    __bf16* lB1 = &Bs[64 + (wv << 4)][0];

    f32x4 acc[4][4] = {};
    const int fr = ln & 15;
    const int fk = (ln >> 4) << 3;

    const int nSteps = kChunk >> 5;
    for (int ks = 0; ks < nSteps; ++ks) {
        gload_lds16(gA0, lA0);
        gload_lds16(gA1, lA1);
        gload_lds16(gB0, lB0);
        gload_lds16(gB1, lB1);
        gA0 += 32; gA1 += 32; gB0 += 32; gB1 += 32;
        __syncthreads();

        bf16x8 af[4], bfr[4];
        #pragma unroll
        for (int m = 0; m < 4; ++m)
            af[m] = *(const bf16x8*)&As[(wr << 6) + (m << 4) + fr][fk];
        #pragma unroll
        for (int n = 0; n < 4; ++n)
            bfr[n] = *(const bf16x8*)&Bs[(wc << 6) + (n << 4) + fr][fk];
        #pragma unroll
        for (int m = 0; m < 4; ++m)
            #pragma unroll
            for (int n = 0; n < 4; ++n)
                acc[m][n] = MFMA16(af[m], bfr[n], acc[m][n]);
        __syncthreads();
    }

    const int cr = (ln >> 4) << 2;
    const int cc = ln & 15;
    #pragma unroll
    for (int n = 0; n < 4; ++n) {
        const int col = (int)(n0) + (wc << 6) + (n << 4) + cc;
        if (col < colMax) {
            #pragma unroll
            for (int m = 0; m < 4; ++m) {
                const size_t row = m0 + (wr << 6) + (m << 4) + cr;
                #pragma unroll
                for (int r = 0; r < 4; ++r)
                    C[(row + r) * (size_t)ldc + col] = acc[m][n][r];
            }
        }
    }
}

/* --------- per-token: softmax(LOG) -> w out; g -> XB tail cols ---------
   256 threads = 4 tokens x 64 lanes */
__global__ __launch_bounds__(256) void mole_softmax_g(
    const float* __restrict__ HP, const float* __restrict__ LOG,
    float* __restrict__ wOut, __bf16* __restrict__ XB)
{
    const int t   = blockIdx.x * 4 + (threadIdx.x >> 6);
    const int tid = threadIdx.x & 63;
    float h = 0.0f;
    #pragma unroll
    for (int sp = 0; sp < NSPLIT; ++sp)
        h += HP[((size_t)sp * BT + t) * HLD + 8 + tid];

    float lg[NEXP];
    #pragma unroll
    for (int e = 0; e < NEXP; ++e) lg[e] = LOG[(size_t)t * NEXP + e];
    float mx = lg[0];
    #pragma unroll
    for (int e = 1; e < NEXP; ++e) mx = fmaxf(mx, lg[e]);
    float ex[NEXP], den = 0.0f;
    #pragma unroll
    for (int e = 0; e < NEXP; ++e) { ex[e] = expf(lg[e] - mx); den += ex[e]; }

    const float w_my = ex[tid >> 3] / den;
    XB[(size_t)t * KX + DIN + tid] = (__bf16)(SCALING * w_my * h);
    if (tid < NEXP) wOut[(size_t)t * NEXP + tid] = ex[tid] / den;
}

/* ===== main 256x256 GEMM: ring-4 BK=32, counted vmcnt, reg-dbuf frags ====
   C[8192,2048] = XB[8192,KX] * WB[2048,KX]^T + bias
   8 waves (2M x 4N), per-wave 128x64 out. LDS = 4 ring slots x 32 KB
   ([A 256x32 | B 256x32] bf16, 64 B/row).
   Swizzle: phys16B(row,k) = k ^ ((row>>1)&3) (2-way bank aliasing = free).
   Step s: vmcnt(4) [slot s+1 landed] -> barrier [published] ->
           stage slot s+3 -> 32 MFMA on regs (read last step!) ->
           12 ds_read slot s+1 -> regs[nxt]  (latency hides under next
           step's barrier crossing; compiler inserts counted lgkm).
   WAR safe: stage(s+3) hits slot s-1, whose reads were lgkm-drained
   before step s-1's MFMAs, which precede barrier s. Never vmcnt(0)
   until the 2-step tail (T4). */
__global__ __launch_bounds__(512, 1) void mole_gemm256(
    const __bf16* __restrict__ XBp, const __bf16* __restrict__ WBp,
    float* __restrict__ C, const float* __restrict__ bias)
{
    __shared__ __align__(16) char smem[131072];

    const int tid = threadIdx.x;
    const int wv  = tid >> 6, l = tid & 63;
    const int wm  = wv >> 2, wn = wv & 3;
    const int bid = blockIdx.x;
    /* T1: XCD x (= bid&7) owns tm in [4x,4x+4) x all tn */
    const int xcd = bid & 7, ib = bid >> 3;
    const int tm = xcd * 4 + (ib & 3), tn = ib >> 2;
    const size_t m0 = (size_t)tm * 256, n0 = (size_t)tn * 256;

    /* staging: waves 0-3 stage A rows, waves 4-7 stage B rows. */
    const int op = wv >> 2, ww = wv & 3;
    const __bf16* gstage = (op == 0 ? XBp + (m0 + ww * 64) * KX
                                    : WBp + (n0 + ww * 64) * KX)
                         + (size_t)(l >> 2) * KX + (((l & 3) ^ ((l >> 3) & 3)) << 3);
    const int stageBase = op * 16384 + ww * 4096;

    /* fragment read: row R, logical k-slot fq -> phys slot fq ^ ((R>>1)&3) */
    const int fr = l & 15, fq = l >> 4;
    const int swz = (fq ^ ((fr >> 1) & 3)) << 4;
    const int aByte = (wm * 128 + fr) * 64 + swz;
    const int bByte = 16384 + (wn * 64 + fr) * 64 + swz;

    f32x4 acc[8][4] = {};
    bf16x8 fa0[8], fb0[4], fa1[8], fb1[4];

#define STAGE(S)                                                              \
    {                                                                         \
        char* dst = smem + ((S) & 3) * 32768 + stageBase;                     \
        const __bf16* g = gstage + (size_t)(S) * 32;                          \
        _Pragma("unroll")                                                     \
        for (int j = 0; j < 4; ++j)                                           \
            gload_lds16(g + (size_t)j * 16 * KX, dst + j * 1024);             \
    }

#define READS(S, FA, FB)                                                      \
    {                                                                         \
        const char* slot = smem + ((S) & 3) * 32768;                          \
        _Pragma("unroll")                                                     \
        for (int nf = 0; nf < 4; ++nf)                                        \
            FB[nf] = *(const bf16x8*)(slot + bByte + nf * 1024);              \
        _Pragma("unroll")                                                     \
        for (int mf = 0; mf < 8; ++mf)                                        \
            FA[mf] = *(const bf16x8*)(slot + aByte + mf * 1024);              \
    }

#define STEP(S, VMN, DOSTAGE, DOREAD, FAc, FBc, FAn, FBn)                     \
    {                                                                         \
        asm volatile("s_waitcnt vmcnt(" #VMN ")" ::: "memory");               \
        __builtin_amdgcn_s_barrier();                                         \
        if (DOSTAGE) STAGE((S) + 3);                                          \
        __builtin_amdgcn_s_setprio(1);                                        \
        _Pragma("unroll")                                                     \
        for (int mf = 0; mf < 8; ++mf)                                        \
            _Pragma("unroll")                                                 \
            for (int nf = 0; nf < 4; ++nf)                                    \
                acc[mf][nf] = MFMA16(FAc[mf], FBc[nf], acc[mf][nf]);          \
        __builtin_amdgcn_s_setprio(0);                                        \
        if (DOREAD) READS((S) + 1, FAn, FBn);                                 \
    }

    /* prologue: stage slots 0,1,2; wait slot 0; prime regs */
    STAGE(0); STAGE(1); STAGE(2);
    asm volatile("s_waitcnt vmcnt(8)" ::: "memory");
    __builtin_amdgcn_s_barrier();
    READS(0, fa0, fb0);

    #pragma unroll 1
    for (int s = 0; s < 62; s += 2) {
        STEP(s,     4, true, true, fa0, fb0, fa1, fb1);
        STEP(s + 1, 4, true, true, fa1, fb1, fa0, fb0);
    }
    STEP(62, 4, true,  true,  fa0, fb0, fa1, fb1);   /* stages slot 65 */
    STEP(63, 4, false, true,  fa1, fb1, fa0, fb0);
    STEP(64, 0, false, true,  fa0, fb0, fa1, fb1);
    STEP(65, 0, false, false, fa1, fb1, fa0, fb0);
#undef STEP
#undef READS
#undef STAGE

    /* epilogue: C = acc + bias */
    const size_t crow = m0 + wm * 128 + fq * 4;
    const size_t ccol = n0 + wn * 64 + fr;
    #pragma unroll
    for (int nf = 0; nf < 4; ++nf) {
        const float bv = bias[ccol + nf * 16];
        #pragma unroll
        for (int mf = 0; mf < 8; ++mf) {
            float* cp = C + (crow + (size_t)mf * 16) * DOUT + ccol + nf * 16;
            #pragma unroll
            for (int i = 0; i < 4; ++i)
                cp[(size_t)i * DOUT] = acc[mf][nf][i] + bv;
        }
    }
}

extern "C" void kernel_launch(void* const* d_in, const int* in_sizes, int n_in,
                              void* d_out, int out_size, void* d_ws, size_t ws_size,
                              hipStream_t stream) {
    const float* x  = (const float*)d_in[0];
    const float* Wf = (const float*)d_in[1];
    const float* bf = (const float*)d_in[2];
    const float* Wr = (const float*)d_in[3];
    const float* br = (const float*)d_in[4];
    const float* A  = (const float*)d_in[5];
    const float* Bm = (const float*)d_in[6];

    float* out0 = (float*)d_out;
    float* wOut = out0 + (size_t)BT * DOUT;

    char* ws = (char*)d_ws;
    __bf16* XB   = (__bf16*)(ws + XB_OFF);
    __bf16* WB   = (__bf16*)(ws + WB_OFF);
    __bf16* ACAT = (__bf16*)(ws + ACAT_OFF);
    float*  HP   = (float*)(ws + HP_OFF);
    float*  LOG  = (float*)(ws + LOG_OFF);

    /* 1. weights -> bf16 layouts */
    mole_prep<<<4864, 256, 0, stream>>>(Wf, Bm, Wr, A, WB, ACAT);
    /* 2. x -> bf16 (stride KX) + exact fp32 router logits */
    mole_convert_x_logits<<<BT, 512, 0, stream>>>(x, Wr, br, XB, LOG);
    /* 3. h-cat = xb @ ACAT^T, 4-way K-split (256 blocks) */
    mole_gemm_bt<<<dim3(64, 1, NSPLIT), 256, 0, stream>>>(
        XB, KX, ACAT, DIN, HP, HLD, HLD, DIN / NSPLIT, (long long)BT * HLD);
    /* 4. softmax + g into XB tail columns; w to output */
    mole_softmax_g<<<BT / 4, 256, 0, stream>>>(HP, LOG, wOut, XB);
    /* 5. out = [xb|g] @ [Wfb|Bcat]^T + bf  (K = 2112, ring-4 + reg-dbuf) */
    mole_gemm256<<<256, 512, 0, stream>>>(XB, WB, out0, bf);
}

// Round 6
// 136.498 us; speedup vs baseline: 1.0081x; 1.0081x over previous
//
#include <hip/hip_runtime.h>
#include <hip/hip_bf16.h>

#define BT      8192
#define DIN     2048
#define DOUT    2048
#define NEXP    8
#define RANK    8
#define KX      2112         /* DIN + NEXP*RANK */
#define NSUB    66           /* KX / 32 K-subtiles */
#define NSPLIT  4            /* K-split for the h-GEMM */
#define HLD     72           /* HP leading dim */
#define SCALING 1.0f         /* ALPHA / RANK = 8/8 */

typedef __bf16 bf16x8 __attribute__((ext_vector_type(8)));
typedef __bf16 bf16x4 __attribute__((ext_vector_type(4)));
typedef float  f32x4  __attribute__((ext_vector_type(4)));

/* ---- ws layout (bytes) ---- */
#define XB_OFF     0
#define XB_BYTES   (BT * KX * 2)
#define WB_OFF     (XB_OFF + XB_BYTES)
#define WB_BYTES   (DOUT * KX * 2)
#define ACAT_OFF   (WB_OFF + WB_BYTES)
#define ACAT_BYTES (128 * DIN * 2)
#define HP_OFF     (ACAT_OFF + ACAT_BYTES)
#define HP_BYTES   (NSPLIT * BT * HLD * 4)
#define LOG_OFF    (HP_OFF + HP_BYTES)

__device__ __forceinline__ void gload_lds16(const void* g, void* l) {
    __builtin_amdgcn_global_load_lds(
        (__attribute__((address_space(1))) void*)(g),
        (__attribute__((address_space(3))) void*)(l),
        16, 0, 0);
}

#define MFMA16(a, b, c) __builtin_amdgcn_mfma_f32_16x16x32_bf16((a), (b), (c), 0, 0, 0)

/* ------- merged: weights->bf16 layouts  +  x->bf16 + fp32 logits -------
   blocks 0..BT-1: convert token bid; blocks BT..BT+2431: prep jobs. */
__global__ __launch_bounds__(512) void mole_prep_convert(
    const float* __restrict__ x, const float* __restrict__ Wf,
    const float* __restrict__ Bm, const float* __restrict__ Wr,
    const float* __restrict__ A, const float* __restrict__ br,
    __bf16* __restrict__ XB, __bf16* __restrict__ WB,
    __bf16* __restrict__ ACAT, float* __restrict__ LOG)
{
    const int bid = blockIdx.x;
    if (bid < BT) {
        const int t   = bid;
        const int tid = threadIdx.x;
        float4 v = ((const float4*)x)[(size_t)t * 512 + tid];
        bf16x4 b; b[0] = (__bf16)v.x; b[1] = (__bf16)v.y; b[2] = (__bf16)v.z; b[3] = (__bf16)v.w;
        *(bf16x4*)&XB[(size_t)t * KX + (tid << 2)] = b;

        float p[NEXP];
        #pragma unroll
        for (int e = 0; e < NEXP; ++e) {
            float4 w4 = ((const float4*)Wr)[e * 512 + tid];
            p[e] = v.x * w4.x + v.y * w4.y + v.z * w4.z + v.w * w4.w;
        }
        #pragma unroll
        for (int e = 0; e < NEXP; ++e)
            #pragma unroll
            for (int off = 32; off > 0; off >>= 1)
                p[e] += __shfl_down(p[e], off);

        __shared__ float red[8][NEXP];
        const int wv = tid >> 6, ln = tid & 63;
        if (ln == 0) {
            #pragma unroll
            for (int e = 0; e < NEXP; ++e) red[wv][e] = p[e];
        }
        __syncthreads();
        if (tid < NEXP) {
            float s = br[tid];
            #pragma unroll
            for (int w = 0; w < 8; ++w) s += red[w][tid];
            LOG[(size_t)t * NEXP + tid] = s;
        }
    } else {
        const int i = (bid - BT) * 512 + threadIdx.x;
        const int R1 = DOUT * (DIN / 4);
        const int R2 = DOUT * 64;
        if (i < R1) {
            const int o = i >> 9, c4 = i & 511;
            float4 v = ((const float4*)Wf)[(size_t)o * 512 + c4];
            bf16x4 b; b[0] = (__bf16)v.x; b[1] = (__bf16)v.y; b[2] = (__bf16)v.z; b[3] = (__bf16)v.w;
            *(bf16x4*)&WB[(size_t)o * KX + (c4 << 2)] = b;
        } else if (i < R1 + R2) {
            const int j = i - R1;
            const int o = j >> 6, c = j & 63;
            const int e = c >> 3, r = c & 7;
            WB[(size_t)o * KX + DIN + c] = (__bf16)Bm[((size_t)e * DOUT + o) * RANK + r];
        } else {
            const int j = i - (R1 + R2);
            const int r = j >> 9, c4 = j & 511;
            float4 v;
            if (r < 8)        v = ((const float4*)Wr)[(size_t)r * 512 + c4];
            else if (r < 72)  v = ((const float4*)A)[(size_t)(r - 8) * 512 + c4];
            else              v = make_float4(0.f, 0.f, 0.f, 0.f);
            bf16x4 b; b[0] = (__bf16)v.x; b[1] = (__bf16)v.y; b[2] = (__bf16)v.z; b[3] = (__bf16)v.w;
            *(bf16x4*)&ACAT[(size_t)r * DIN + (c4 << 2)] = b;
        }
    }
}

/* ------- 128x128 MFMA GEMM (m97 structure), used for the h-GEMM ------- */
__global__ __launch_bounds__(256) void mole_gemm_bt(
    const __bf16* __restrict__ A, int lda,
    const __bf16* __restrict__ B, int ldb,
    float* __restrict__ C, int ldc, int colMax,
    int kChunk, long long cZStride)
{
    __shared__ __align__(16) __bf16 As[128][32];
    __shared__ __align__(16) __bf16 Bs[128][32];

    const int tid = threadIdx.x;
    const int wv  = tid >> 6;
    const int ln  = tid & 63;
    const int wr  = wv >> 1, wc = wv & 1;

    const size_t m0 = (size_t)blockIdx.x * 128;
    const size_t n0 = (size_t)blockIdx.y * 128;
    const int kStart = blockIdx.z * kChunk;
    C += (long long)blockIdx.z * cZStride;

    const int srow = (wv << 4) + (ln >> 2);
    const int scol = (ln & 3) << 3;
    const __bf16* gA0 = A + (m0 + srow) * (size_t)lda + kStart + scol;
    const __bf16* gA1 = gA0 + (size_t)64 * lda;
    const __bf16* gB0 = B + (n0 + srow) * (size_t)ldb + kStart + scol;
    const __bf16* gB1 = gB0 + (size_t)64 * ldb;
    __bf16* lA0 = &As[(wv << 4)][0];
    __bf16* lA1 = &As[64 + (wv << 4)][0];
    __bf16* lB0 = &Bs[(wv << 4)][0];
    __bf16* lB1 = &Bs[64 + (wv << 4)][0];

    f32x4 acc[4][4] = {};
    const int fr = ln & 15;
    const int fk = (ln >> 4) << 3;

    const int nSteps = kChunk >> 5;
    for (int ks = 0; ks < nSteps; ++ks) {
        gload_lds16(gA0, lA0);
        gload_lds16(gA1, lA1);
        gload_lds16(gB0, lB0);
        gload_lds16(gB1, lB1);
        gA0 += 32; gA1 += 32; gB0 += 32; gB1 += 32;
        __syncthreads();

        bf16x8 af[4], bfr[4];
        #pragma unroll
        for (int m = 0; m < 4; ++m)
            af[m] = *(const bf16x8*)&As[(wr << 6) + (m << 4) + fr][fk];
        #pragma unroll
        for (int n = 0; n < 4; ++n)
            bfr[n] = *(const bf16x8*)&Bs[(wc << 6) + (n << 4) + fr][fk];
        #pragma unroll
        for (int m = 0; m < 4; ++m)
            #pragma unroll
            for (int n = 0; n < 4; ++n)
                acc[m][n] = MFMA16(af[m], bfr[n], acc[m][n]);
        __syncthreads();
    }

    const int cr = (ln >> 4) << 2;
    const int cc = ln & 15;
    #pragma unroll
    for (int n = 0; n < 4; ++n) {
        const int col = (int)(n0) + (wc << 6) + (n << 4) + cc;
        if (col < colMax) {
            #pragma unroll
            for (int m = 0; m < 4; ++m) {
                const size_t row = m0 + (wr << 6) + (m << 4) + cr;
                #pragma unroll
                for (int r = 0; r < 4; ++r)
                    C[(row + r) * (size_t)ldc + col] = acc[m][n][r];
            }
        }
    }
}

/* --------- per-token: softmax(LOG) -> w out; g -> XB tail cols ---------
   256 threads = 4 tokens x 64 lanes */
__global__ __launch_bounds__(256) void mole_softmax_g(
    const float* __restrict__ HP, const float* __restrict__ LOG,
    float* __restrict__ wOut, __bf16* __restrict__ XB)
{
    const int t   = blockIdx.x * 4 + (threadIdx.x >> 6);
    const int tid = threadIdx.x & 63;
    float h = 0.0f;
    #pragma unroll
    for (int sp = 0; sp < NSPLIT; ++sp)
        h += HP[((size_t)sp * BT + t) * HLD + 8 + tid];

    float lg[NEXP];
    #pragma unroll
    for (int e = 0; e < NEXP; ++e) lg[e] = LOG[(size_t)t * NEXP + e];
    float mx = lg[0];
    #pragma unroll
    for (int e = 1; e < NEXP; ++e) mx = fmaxf(mx, lg[e]);
    float ex[NEXP], den = 0.0f;
    #pragma unroll
    for (int e = 0; e < NEXP; ++e) { ex[e] = expf(lg[e] - mx); den += ex[e]; }

    const float w_my = ex[tid >> 3] / den;
    XB[(size_t)t * KX + DIN + tid] = (__bf16)(SCALING * w_my * h);
    if (tid < NEXP) wOut[(size_t)t * NEXP + tid] = ex[tid] / den;
}

/* ===== main 256x256 GEMM: ring-4 BK=32, counted vmcnt, 2-phase steps ====
   C[8192,2048] = XB[8192,KX] * WB[2048,KX]^T + bias
   8 waves (2M x 4N), per-wave 128x64 out. LDS = 4 ring slots x 32 KB
   ([A 256x32 | B 256x32] bf16, 64 B/row).
   Swizzle: phys16B(row,k) = k ^ ((row>>1)&3) (2-way aliasing = free;
   verified conflicts=0). Applied via pre-swizzled global source.
   m201-style phases (2 per sub-tile, 16 MFMA each, 2 barriers each):
     PH0: read fb[0-3]+fa[0-3] (8); vmcnt(4); stage(s+3); BAR;
          lgkm(0)+schedbar; setprio; MFMA mf0-3 x nf0-3; BAR
     PH1: read fa[4-7] (4); BAR; lgkm(0)+schedbar; setprio;
          MFMA mf4-7 x nf0-3; BAR
   Uneven read counts (8/4) create wave skew so LDS bursts overlap MFMA
   bursts across waves (T3+T4 regime). Flight = 3 sub-tiles; vmcnt never
   0 until 2-sub-tile tail. */
__global__ __launch_bounds__(512, 1) void mole_gemm256(
    const __bf16* __restrict__ XBp, const __bf16* __restrict__ WBp,
    float* __restrict__ C, const float* __restrict__ bias)
{
    __shared__ __align__(16) char smem[131072];

    const int tid = threadIdx.x;
    const int wv  = tid >> 6, l = tid & 63;
    const int wm  = wv >> 2, wn = wv & 3;
    const int bid = blockIdx.x;
    /* T1: XCD x (= bid&7) owns tm in [4x,4x+4) x all tn */
    const int xcd = bid & 7, ib = bid >> 3;
    const int tm = xcd * 4 + (ib & 3), tn = ib >> 2;
    const size_t m0 = (size_t)tm * 256, n0 = (size_t)tn * 256;

    /* staging: waves 0-3 stage A rows, waves 4-7 stage B rows. */
    const int op = wv >> 2, ww = wv & 3;
    const __bf16* gstage = (op == 0 ? XBp + (m0 + ww * 64) * KX
                                    : WBp + (n0 + ww * 64) * KX)
                         + (size_t)(l >> 2) * KX + (((l & 3) ^ ((l >> 3) & 3)) << 3);
    const int stageBase = op * 16384 + ww * 4096;

    /* fragment read: row R, logical k-slot fq -> phys slot fq ^ ((R>>1)&3) */
    const int fr = l & 15, fq = l >> 4;
    const int swz = (fq ^ ((fr >> 1) & 3)) << 4;
    const int aByte = (wm * 128 + fr) * 64 + swz;
    const int bByte = 16384 + (wn * 64 + fr) * 64 + swz;

    f32x4 acc[8][4] = {};
    bf16x8 fa[4], fb[4];

#define STAGE(S)                                                              \
    {                                                                         \
        char* dst = smem + ((S) & 3) * 32768 + stageBase;                     \
        const __bf16* g = gstage + (size_t)(S) * 32;                          \
        _Pragma("unroll")                                                     \
        for (int j = 0; j < 4; ++j)                                           \
            gload_lds16(g + (size_t)j * 16 * KX, dst + j * 1024);             \
    }

#define PH0(S, VMN, DOSTAGE)                                                  \
    {                                                                         \
        const char* slot = smem + ((S) & 3) * 32768;                          \
        _Pragma("unroll")                                                     \
        for (int nf = 0; nf < 4; ++nf)                                        \
            fb[nf] = *(const bf16x8*)(slot + bByte + nf * 1024);              \
        _Pragma("unroll")                                                     \
        for (int mf = 0; mf < 4; ++mf)                                        \
            fa[mf] = *(const bf16x8*)(slot + aByte + mf * 1024);              \
        asm volatile("s_waitcnt vmcnt(" #VMN ")" ::: "memory");               \
        if (DOSTAGE) STAGE((S) + 3);                                          \
        __builtin_amdgcn_s_barrier();                                         \
        asm volatile("s_waitcnt lgkmcnt(0)" ::: "memory");                    \
        __builtin_amdgcn_sched_barrier(0);                                    \
        __builtin_amdgcn_s_setprio(1);                                        \
        _Pragma("unroll")                                                     \
        for (int mf = 0; mf < 4; ++mf)                                        \
            _Pragma("unroll")                                                 \
            for (int nf = 0; nf < 4; ++nf)                                    \
                acc[mf][nf] = MFMA16(fa[mf], fb[nf], acc[mf][nf]);            \
        __builtin_amdgcn_s_setprio(0);                                        \
        __builtin_amdgcn_s_barrier();                                         \
    }

#define PH1(S)                                                                \
    {                                                                         \
        const char* slot = smem + ((S) & 3) * 32768;                          \
        _Pragma("unroll")                                                     \
        for (int mf = 0; mf < 4; ++mf)                                        \
            fa[mf] = *(const bf16x8*)(slot + aByte + (4 + mf) * 1024);        \
        __builtin_amdgcn_s_barrier();                                         \
        asm volatile("s_waitcnt lgkmcnt(0)" ::: "memory");                    \
        __builtin_amdgcn_sched_barrier(0);                                    \
        __builtin_amdgcn_s_setprio(1);                                        \
        _Pragma("unroll")                                                     \
        for (int mf = 0; mf < 4; ++mf)                                        \
            _Pragma("unroll")                                                 \
            for (int nf = 0; nf < 4; ++nf)                                    \
                acc[4 + mf][nf] = MFMA16(fa[mf], fb[nf], acc[4 + mf][nf]);    \
        __builtin_amdgcn_s_setprio(0);                                        \
        __builtin_amdgcn_s_barrier();                                         \
    }

    /* prologue: stage slots 0,1,2; wait slot 0; publish */
    STAGE(0); STAGE(1); STAGE(2);
    asm volatile("s_waitcnt vmcnt(8)" ::: "memory");
    __builtin_amdgcn_s_barrier();

    #pragma unroll 1
    for (int s = 0; s < NSUB - 3; ++s) {
        PH0(s, 4, true);
        PH1(s);
    }
    PH0(NSUB - 3, 4, false); PH1(NSUB - 3);
    PH0(NSUB - 2, 0, false); PH1(NSUB - 2);
    PH0(NSUB - 1, 0, false); PH1(NSUB - 1);
#undef PH0
#undef PH1
#undef STAGE

    /* epilogue: C = acc + bias */
    const size_t crow = m0 + wm * 128 + fq * 4;
    const size_t ccol = n0 + wn * 64 + fr;
    #pragma unroll
    for (int nf = 0; nf < 4; ++nf) {
        const float bv = bias[ccol + nf * 16];
        #pragma unroll
        for (int mf = 0; mf < 8; ++mf) {
            float* cp = C + (crow + (size_t)mf * 16) * DOUT + ccol + nf * 16;
            #pragma unroll
            for (int i = 0; i < 4; ++i)
                cp[(size_t)i * DOUT] = acc[mf][nf][i] + bv;
        }
    }
}

extern "C" void kernel_launch(void* const* d_in, const int* in_sizes, int n_in,
                              void* d_out, int out_size, void* d_ws, size_t ws_size,
                              hipStream_t stream) {
    const float* x  = (const float*)d_in[0];
    const float* Wf = (const float*)d_in[1];
    const float* bf = (const float*)d_in[2];
    const float* Wr = (const float*)d_in[3];
    const float* br = (const float*)d_in[4];
    const float* A  = (const float*)d_in[5];
    const float* Bm = (const float*)d_in[6];

    float* out0 = (float*)d_out;
    float* wOut = out0 + (size_t)BT * DOUT;

    char* ws = (char*)d_ws;
    __bf16* XB   = (__bf16*)(ws + XB_OFF);
    __bf16* WB   = (__bf16*)(ws + WB_OFF);
    __bf16* ACAT = (__bf16*)(ws + ACAT_OFF);
    float*  HP   = (float*)(ws + HP_OFF);
    float*  LOG  = (float*)(ws + LOG_OFF);

    /* 1. weights -> bf16 layouts  +  x -> bf16 + fp32 router logits */
    mole_prep_convert<<<BT + 2432, 512, 0, stream>>>(
        x, Wf, Bm, Wr, A, br, XB, WB, ACAT, LOG);
    /* 2. h-cat = xb @ ACAT^T, 4-way K-split (256 blocks) */
    mole_gemm_bt<<<dim3(64, 1, NSPLIT), 256, 0, stream>>>(
        XB, KX, ACAT, DIN, HP, HLD, HLD, DIN / NSPLIT, (long long)BT * HLD);
    /* 3. softmax + g into XB tail columns; w to output */
    mole_softmax_g<<<BT / 4, 256, 0, stream>>>(HP, LOG, wOut, XB);
    /* 4. out = [xb|g] @ [Wfb|Bcat]^T + bf  (K = 2112, ring-4 2-phase) */
    mole_gemm256<<<256, 512, 0, stream>>>(XB, WB, out0, bf);
}

// Round 7
// 126.725 us; speedup vs baseline: 1.0859x; 1.0771x over previous
//
#include <hip/hip_runtime.h>
#include <hip/hip_bf16.h>

#define BT      8192
#define DIN     2048
#define DOUT    2048
#define NEXP    8
#define RANK    8
#define KX      2112         /* DIN + NEXP*RANK */
#define NT64    33           /* KX / 64 K-tiles */
#define NSPLIT  4            /* K-split for the h-GEMM */
#define HLD     72           /* HP leading dim */
#define SCALING 1.0f         /* ALPHA / RANK = 8/8 */

typedef __bf16 bf16x8 __attribute__((ext_vector_type(8)));
typedef __bf16 bf16x4 __attribute__((ext_vector_type(4)));
typedef float  f32x4  __attribute__((ext_vector_type(4)));

/* ---- ws layout (bytes) ---- */
#define XB_OFF     0
#define XB_BYTES   (BT * KX * 2)
#define WB_OFF     (XB_OFF + XB_BYTES)
#define WB_BYTES   (DOUT * KX * 2)
#define ACAT_OFF   (WB_OFF + WB_BYTES)
#define ACAT_BYTES (128 * DIN * 2)
#define HP_OFF     (ACAT_OFF + ACAT_BYTES)
#define HP_BYTES   (NSPLIT * BT * HLD * 4)
#define LOG_OFF    (HP_OFF + HP_BYTES)

__device__ __forceinline__ void gload_lds16(const void* g, void* l) {
    __builtin_amdgcn_global_load_lds(
        (__attribute__((address_space(1))) void*)(g),
        (__attribute__((address_space(3))) void*)(l),
        16, 0, 0);
}

#define MFMA16(a, b, c) __builtin_amdgcn_mfma_f32_16x16x32_bf16((a), (b), (c), 0, 0, 0)

/* ------- merged: weights->bf16 layouts  +  x->bf16 + fp32 logits ------- */
__global__ __launch_bounds__(512) void mole_prep_convert(
    const float* __restrict__ x, const float* __restrict__ Wf,
    const float* __restrict__ Bm, const float* __restrict__ Wr,
    const float* __restrict__ A, const float* __restrict__ br,
    __bf16* __restrict__ XB, __bf16* __restrict__ WB,
    __bf16* __restrict__ ACAT, float* __restrict__ LOG)
{
    const int bid = blockIdx.x;
    if (bid < BT) {
        const int t   = bid;
        const int tid = threadIdx.x;
        float4 v = ((const float4*)x)[(size_t)t * 512 + tid];
        bf16x4 b; b[0] = (__bf16)v.x; b[1] = (__bf16)v.y; b[2] = (__bf16)v.z; b[3] = (__bf16)v.w;
        *(bf16x4*)&XB[(size_t)t * KX + (tid << 2)] = b;

        float p[NEXP];
        #pragma unroll
        for (int e = 0; e < NEXP; ++e) {
            float4 w4 = ((const float4*)Wr)[e * 512 + tid];
            p[e] = v.x * w4.x + v.y * w4.y + v.z * w4.z + v.w * w4.w;
        }
        #pragma unroll
        for (int e = 0; e < NEXP; ++e)
            #pragma unroll
            for (int off = 32; off > 0; off >>= 1)
                p[e] += __shfl_down(p[e], off);

        __shared__ float red[8][NEXP];
        const int wv = tid >> 6, ln = tid & 63;
        if (ln == 0) {
            #pragma unroll
            for (int e = 0; e < NEXP; ++e) red[wv][e] = p[e];
        }
        __syncthreads();
        if (tid < NEXP) {
            float s = br[tid];
            #pragma unroll
            for (int w = 0; w < 8; ++w) s += red[w][tid];
            LOG[(size_t)t * NEXP + tid] = s;
        }
    } else {
        const int i = (bid - BT) * 512 + threadIdx.x;
        const int R1 = DOUT * (DIN / 4);
        const int R2 = DOUT * 64;
        if (i < R1) {
            const int o = i >> 9, c4 = i & 511;
            float4 v = ((const float4*)Wf)[(size_t)o * 512 + c4];
            bf16x4 b; b[0] = (__bf16)v.x; b[1] = (__bf16)v.y; b[2] = (__bf16)v.z; b[3] = (__bf16)v.w;
            *(bf16x4*)&WB[(size_t)o * KX + (c4 << 2)] = b;
        } else if (i < R1 + R2) {
            const int j = i - R1;
            const int o = j >> 6, c = j & 63;
            const int e = c >> 3, r = c & 7;
            WB[(size_t)o * KX + DIN + c] = (__bf16)Bm[((size_t)e * DOUT + o) * RANK + r];
        } else {
            const int j = i - (R1 + R2);
            const int r = j >> 9, c4 = j & 511;
            float4 v;
            if (r < 8)        v = ((const float4*)Wr)[(size_t)r * 512 + c4];
            else if (r < 72)  v = ((const float4*)A)[(size_t)(r - 8) * 512 + c4];
            else              v = make_float4(0.f, 0.f, 0.f, 0.f);
            bf16x4 b; b[0] = (__bf16)v.x; b[1] = (__bf16)v.y; b[2] = (__bf16)v.z; b[3] = (__bf16)v.w;
            *(bf16x4*)&ACAT[(size_t)r * DIN + (c4 << 2)] = b;
        }
    }
}

/* ------- 128x128 MFMA GEMM (m97 structure), used for the h-GEMM ------- */
__global__ __launch_bounds__(256) void mole_gemm_bt(
    const __bf16* __restrict__ A, int lda,
    const __bf16* __restrict__ B, int ldb,
    float* __restrict__ C, int ldc, int colMax,
    int kChunk, long long cZStride)
{
    __shared__ __align__(16) __bf16 As[128][32];
    __shared__ __align__(16) __bf16 Bs[128][32];

    const int tid = threadIdx.x;
    const int wv  = tid >> 6;
    const int ln  = tid & 63;
    const int wr  = wv >> 1, wc = wv & 1;

    const size_t m0 = (size_t)blockIdx.x * 128;
    const size_t n0 = (size_t)blockIdx.y * 128;
    const int kStart = blockIdx.z * kChunk;
    C += (long long)blockIdx.z * cZStride;

    const int srow = (wv << 4) + (ln >> 2);
    const int scol = (ln & 3) << 3;
    const __bf16* gA0 = A + (m0 + srow) * (size_t)lda + kStart + scol;
    const __bf16* gA1 = gA0 + (size_t)64 * lda;
    const __bf16* gB0 = B + (n0 + srow) * (size_t)ldb + kStart + scol;
    const __bf16* gB1 = gB0 + (size_t)64 * ldb;
    __bf16* lA0 = &As[(wv << 4)][0];
    __bf16* lA1 = &As[64 + (wv << 4)][0];
    __bf16* lB0 = &Bs[(wv << 4)][0];
    __bf16* lB1 = &Bs[64 + (wv << 4)][0];

    f32x4 acc[4][4] = {};
    const int fr = ln & 15;
    const int fk = (ln >> 4) << 3;

    const int nSteps = kChunk >> 5;
    for (int ks = 0; ks < nSteps; ++ks) {
        gload_lds16(gA0, lA0);
        gload_lds16(gA1, lA1);
        gload_lds16(gB0, lB0);
        gload_lds16(gB1, lB1);
        gA0 += 32; gA1 += 32; gB0 += 32; gB1 += 32;
        __syncthreads();

        bf16x8 af[4], bfr[4];
        #pragma unroll
        for (int m = 0; m < 4; ++m)
            af[m] = *(const bf16x8*)&As[(wr << 6) + (m << 4) + fr][fk];
        #pragma unroll
        for (int n = 0; n < 4; ++n)
            bfr[n] = *(const bf16x8*)&Bs[(wc << 6) + (n << 4) + fr][fk];
        #pragma unroll
        for (int m = 0; m < 4; ++m)
            #pragma unroll
            for (int n = 0; n < 4; ++n)
                acc[m][n] = MFMA16(af[m], bfr[n], acc[m][n]);
        __syncthreads();
    }

    const int cr = (ln >> 4) << 2;
    const int cc = ln & 15;
    #pragma unroll
    for (int n = 0; n < 4; ++n) {
        const int col = (int)(n0) + (wc << 6) + (n << 4) + cc;
        if (col < colMax) {
            #pragma unroll
            for (int m = 0; m < 4; ++m) {
                const size_t row = m0 + (wr << 6) + (m << 4) + cr;
                #pragma unroll
                for (int r = 0; r < 4; ++r)
                    C[(row + r) * (size_t)ldc + col] = acc[m][n][r];
            }
        }
    }
}

/* --------- per-token: softmax(LOG) -> w out; g -> XB tail cols --------- */
__global__ __launch_bounds__(256) void mole_softmax_g(
    const float* __restrict__ HP, const float* __restrict__ LOG,
    float* __restrict__ wOut, __bf16* __restrict__ XB)
{
    const int t   = blockIdx.x * 4 + (threadIdx.x >> 6);
    const int tid = threadIdx.x & 63;
    float h = 0.0f;
    #pragma unroll
    for (int sp = 0; sp < NSPLIT; ++sp)
        h += HP[((size_t)sp * BT + t) * HLD + 8 + tid];

    float lg[NEXP];
    #pragma unroll
    for (int e = 0; e < NEXP; ++e) lg[e] = LOG[(size_t)t * NEXP + e];
    float mx = lg[0];
    #pragma unroll
    for (int e = 1; e < NEXP; ++e) mx = fmaxf(mx, lg[e]);
    float ex[NEXP], den = 0.0f;
    #pragma unroll
    for (int e = 0; e < NEXP; ++e) { ex[e] = expf(lg[e] - mx); den += ex[e]; }

    const float w_my = ex[tid >> 3] / den;
    XB[(size_t)t * KX + DIN + tid] = (__bf16)(SCALING * w_my * h);
    if (tid < NEXP) wOut[(size_t)t * NEXP + tid] = ex[tid] / den;
}

/* ========== main 256x256 GEMM: m201-style BK=64 dbuf, counted vmcnt =====
   C[8192,2048] = XB[8192,KX] * WB[2048,KX]^T + bias
   8 waves (2M x 4N), per-wave 128x64. LDS 128KB = 2 buf x (A 256x128B +
   B 256x128B). Swizzle: phys16B(row,s) = s ^ (row&7), 0-conflict
   (verified R4); staged via pre-swizzled global col ((l&7)^(l>>3))*8.
   Per tile (BK=64), 3 sync points, quarters staged by next-phase need:
     ph0: read fa(mf0-3,kk01)+fb(nf0-1) [12]; stage Qa'(4); vmcnt(6); BAR;
          lgkm0; 16 MFMA
     ph1: read fb2(nf2-3) [4]; stage Qb'(2); vmcnt(6); BAR; lgkm0; 16 MFMA
     ph2+3: read fa2(mf4-7) [8]; stage Qc'(2); 32 MFMA (compiler lgkm);
          vmcnt(4); BAR
   Ledger: Qa=ph0-need (A r0-63,128-191 + B nf0-1 rows), Qb=B nf2-3 rows,
   Qc=A r64-127,192-255. Each quarter vmcnt-complete + barrier-published
   exactly 1 phase before first read. vmcnt never 0 until peeled tail. */
__global__ __launch_bounds__(512, 1) void mole_gemm256(
    const __bf16* __restrict__ XBp, const __bf16* __restrict__ WBp,
    float* __restrict__ C, const float* __restrict__ bias)
{
    __shared__ __align__(16) char smem[131072];

    const int tid = threadIdx.x;
    const int wv  = tid >> 6, l = tid & 63;
    const int wm  = wv >> 2, wn = wv & 3;
    const int bid = blockIdx.x;
    /* T1: XCD x (= bid&7) owns tm in [4x,4x+4) x all tn (FETCH 51 MB) */
    const int xcd = bid & 7, ib = bid >> 3;
    const int tm = xcd * 4 + (ib & 3), tn = ib >> 2;
    const size_t m0 = (size_t)tm * 256, n0 = (size_t)tn * 256;

    /* staging lane geometry: lane l -> row +(l>>3), phys slot l&7,
       logical col ((l&7)^(l>>3))*8 (inverse of read swizzle) */
    const __bf16* gA = XBp + (m0 + (l >> 3)) * KX + (((l & 7) ^ (l >> 3)) << 3);
    const __bf16* gB = WBp + (n0 + (l >> 3)) * KX + (((l & 7) ^ (l >> 3)) << 3);

    const int rA0 = wv * 8;                             /* Qa-A rows, +128   */
    const int rB0 = ((wv & 3) * 8) + ((wv >> 2) * 64);  /* Qa-B rows, +128   */
    const int rC0 = 64 + wv * 8;                        /* Qc-A rows, +128   */

    /* fragment read: row base + fr, phys slot (kk*4+fq)^(fr&7) */
    const int fr = l & 15, fq = l >> 4;
    const int sw0 = ((fq)     ^ (fr & 7)) << 4;
    const int sw1 = ((4 + fq) ^ (fr & 7)) << 4;
    const int aOff = (wm * 128 + fr) * 128;
    const int bOff = 32768 + (wn * 64 + fr) * 128;

    f32x4 acc[8][4] = {};
    bf16x8 fa[4][2], fa2[4][2], fb[2][2], fb2[2][2];

#define GL(gsrc, R, T, q, isB)                                                \
    gload_lds16((gsrc) + (size_t)(R) * KX + (size_t)(T) * 64,                 \
                smem + (q) * 65536 + ((isB) ? 32768 : 0) + (R) * 128)

#define STQA(T, q) { GL(gA, rA0, T, q, 0); GL(gA, rA0 + 128, T, q, 0);        \
                     GL(gB, rB0, T, q, 1); GL(gB, rB0 + 128, T, q, 1); }
#define STQB(T, q) { GL(gB, rB0 + 32, T, q, 1); GL(gB, rB0 + 160, T, q, 1); }
#define STQC(T, q) { GL(gA, rC0, T, q, 0); GL(gA, rC0 + 128, T, q, 0); }

#define RD_FA(arr, base, ab)                                                  \
    _Pragma("unroll")                                                         \
    for (int mf = 0; mf < 4; ++mf) {                                          \
        arr[mf][0] = *(const bf16x8*)((ab) + ((base) + mf) * 2048 + sw0);     \
        arr[mf][1] = *(const bf16x8*)((ab) + ((base) + mf) * 2048 + sw1);     \
    }
#define RD_FB(arr, base, bb)                                                  \
    _Pragma("unroll")                                                         \
    for (int nf = 0; nf < 2; ++nf) {                                          \
        arr[nf][0] = *(const bf16x8*)((bb) + ((base) + nf) * 2048 + sw0);     \
        arr[nf][1] = *(const bf16x8*)((bb) + ((base) + nf) * 2048 + sw1);     \
    }
#define MM16(FA, FB, MB, NB)                                                  \
    __builtin_amdgcn_s_setprio(1);                                            \
    _Pragma("unroll")                                                         \
    for (int kk = 0; kk < 2; ++kk)                                            \
        _Pragma("unroll")                                                     \
        for (int mf = 0; mf < 4; ++mf)                                        \
            _Pragma("unroll")                                                 \
            for (int nf = 0; nf < 2; ++nf)                                    \
                acc[(MB) + mf][(NB) + nf] =                                   \
                    MFMA16(FA[mf][kk], FB[nf][kk], acc[(MB) + mf][(NB) + nf]);\
    __builtin_amdgcn_s_setprio(0);
#define WAITBAR(VMN)                                                          \
    asm volatile("s_waitcnt vmcnt(" #VMN ")" ::: "memory");                   \
    __builtin_amdgcn_s_barrier();                                             \
    asm volatile("s_waitcnt lgkmcnt(0)" ::: "memory");                        \
    __builtin_amdgcn_sched_barrier(0);

    /* prologue: stage tile 0 -> buf 0 (8 loads); Qa0 complete; publish */
    STQA(0, 0); STQB(0, 0); STQC(0, 0);
    asm volatile("s_waitcnt vmcnt(4)" ::: "memory");
    __builtin_amdgcn_s_barrier();

    #pragma unroll 1
    for (int t = 0; t < NT64 - 1; ++t) {
        const int p = t & 1, q = p ^ 1;
        const char* ab = smem + p * 65536 + aOff;
        const char* bb = smem + p * 65536 + bOff;
        /* ph0 */
        RD_FA(fa, 0, ab);
        RD_FB(fb, 0, bb);
        STQA(t + 1, q);
        WAITBAR(6);
        MM16(fa, fb, 0, 0);
        /* ph1 */
        RD_FB(fb2, 2, bb);
        STQB(t + 1, q);
        WAITBAR(6);
        MM16(fa, fb2, 0, 2);
        /* ph2+3 */
        RD_FA(fa2, 4, ab);
        STQC(t + 1, q);
        MM16(fa2, fb, 4, 0);
        MM16(fa2, fb2, 4, 2);
        asm volatile("s_waitcnt vmcnt(4)" ::: "memory");
        __builtin_amdgcn_s_barrier();
    }
    /* tail tile 32 (buf 0), no staging */
    {
        const char* ab = smem + 0 * 65536 + aOff;
        const char* bb = smem + 0 * 65536 + bOff;
        RD_FA(fa, 0, ab);
        RD_FB(fb, 0, bb);
        WAITBAR(2);
        MM16(fa, fb, 0, 0);
        RD_FB(fb2, 2, bb);
        WAITBAR(0);
        MM16(fa, fb2, 0, 2);
        RD_FA(fa2, 4, ab);
        MM16(fa2, fb, 4, 0);
        MM16(fa2, fb2, 4, 2);
    }
#undef GL
#undef STQA
#undef STQB
#undef STQC
#undef RD_FA
#undef RD_FB
#undef MM16
#undef WAITBAR

    /* epilogue: C = acc + bias */
    const size_t crow = m0 + wm * 128 + fq * 4;
    const size_t ccol = n0 + wn * 64 + fr;
    #pragma unroll
    for (int nf = 0; nf < 4; ++nf) {
        const float bv = bias[ccol + nf * 16];
        #pragma unroll
        for (int mf = 0; mf < 8; ++mf) {
            float* cp = C + (crow + (size_t)mf * 16) * DOUT + ccol + nf * 16;
            #pragma unroll
            for (int i = 0; i < 4; ++i)
                cp[(size_t)i * DOUT] = acc[mf][nf][i] + bv;
        }
    }
}

extern "C" void kernel_launch(void* const* d_in, const int* in_sizes, int n_in,
                              void* d_out, int out_size, void* d_ws, size_t ws_size,
                              hipStream_t stream) {
    const float* x  = (const float*)d_in[0];
    const float* Wf = (const float*)d_in[1];
    const float* bf = (const float*)d_in[2];
    const float* Wr = (const float*)d_in[3];
    const float* br = (const float*)d_in[4];
    const float* A  = (const float*)d_in[5];
    const float* Bm = (const float*)d_in[6];

    float* out0 = (float*)d_out;
    float* wOut = out0 + (size_t)BT * DOUT;

    char* ws = (char*)d_ws;
    __bf16* XB   = (__bf16*)(ws + XB_OFF);
    __bf16* WB   = (__bf16*)(ws + WB_OFF);
    __bf16* ACAT = (__bf16*)(ws + ACAT_OFF);
    float*  HP   = (float*)(ws + HP_OFF);
    float*  LOG  = (float*)(ws + LOG_OFF);

    /* 1. weights -> bf16 layouts  +  x -> bf16 + fp32 router logits */
    mole_prep_convert<<<BT + 2432, 512, 0, stream>>>(
        x, Wf, Bm, Wr, A, br, XB, WB, ACAT, LOG);
    /* 2. h-cat = xb @ ACAT^T, 4-way K-split (256 blocks) */
    mole_gemm_bt<<<dim3(64, 1, NSPLIT), 256, 0, stream>>>(
        XB, KX, ACAT, DIN, HP, HLD, HLD, DIN / NSPLIT, (long long)BT * HLD);
    /* 3. softmax + g into XB tail columns; w to output */
    mole_softmax_g<<<BT / 4, 256, 0, stream>>>(HP, LOG, wOut, XB);
    /* 4. out = [xb|g] @ [Wfb|Bcat]^T + bf  (K = 2112, BK=64 m201-style) */
    mole_gemm256<<<256, 512, 0, stream>>>(XB, WB, out0, bf);
}